// Round 1
// baseline (589.528 us; speedup 1.0000x reference)
//
#include <hip/hip_runtime.h>
#include <hip/hip_bf16.h>
#include <math.h>

#define NEG_SLOPE 0.2f
#define RECON_W 0.1f
#define BN_EPS 1e-5f

// ---------------------------------------------------------------- CSR build
__global__ void count_kernel(const int* __restrict__ dst, int E, int* __restrict__ deg) {
    int e = blockIdx.x * blockDim.x + threadIdx.x;
    if (e < E) atomicAdd(&deg[dst[e]], 1);
}

__global__ __launch_bounds__(1024) void scan_kernel(const int* __restrict__ deg,
                                                    int* __restrict__ rowptr, int N) {
    __shared__ int wsum[16];
    __shared__ int s_tot;
    int tid = threadIdx.x;
    int lane = tid & 63;
    int w = tid >> 6;
    int running = 0;
    for (int base = 0; base < N; base += 1024) {
        int i = base + tid;
        int v = (i < N) ? deg[i] : 0;
        int inc = v;
        #pragma unroll
        for (int off = 1; off < 64; off <<= 1) {
            int t = __shfl_up(inc, off);
            if (lane >= off) inc += t;
        }
        if (lane == 63) wsum[w] = inc;
        __syncthreads();
        if (tid == 0) {
            int r = 0;
            #pragma unroll
            for (int j = 0; j < 16; j++) { int t = wsum[j]; wsum[j] = r; r += t; }
            s_tot = r;
        }
        __syncthreads();
        int excl = running + wsum[w] + inc - v;
        if (i < N) rowptr[i] = excl;
        running += s_tot;
        __syncthreads();   // protect wsum before next iteration
    }
    if (tid == 0) rowptr[N] = running;
}

__global__ void scatter_kernel(const int* __restrict__ src, const int* __restrict__ dst, int E,
                               const int* __restrict__ rowptr, int* __restrict__ cursor,
                               int* __restrict__ csr_src) {
    int e = blockIdx.x * blockDim.x + threadIdx.x;
    if (e < E) {
        int d = dst[e];
        int pos = rowptr[d] + atomicAdd(&cursor[d], 1);
        csr_src[pos] = src[e];
    }
}

// ---------------------------------------------------------------- GEMM1: h1 = x @ W1 (+ alpha epilogue)
// x:[N,128], W1:[128,128] -> h1:[N,128]; alpha_src1/dst1:[N,4]
__global__ __launch_bounds__(256) void gemm1_kernel(
    const float* __restrict__ x, const float* __restrict__ W,
    const float* __restrict__ a_src, const float* __restrict__ a_dst,
    float* __restrict__ h1, float* __restrict__ as1, float* __restrict__ ad1, int N) {
    __shared__ float As[64][33];
    __shared__ float Bs[32][128];
    int tid = threadIdx.x;
    int tx = tid & 15;   // col group: cols tx*8 .. tx*8+7
    int ty = tid >> 4;   // row group: rows ty*4 .. ty*4+3
    int rowBase = blockIdx.x * 64;
    float acc[4][8];
    #pragma unroll
    for (int i = 0; i < 4; i++)
        #pragma unroll
        for (int j = 0; j < 8; j++) acc[i][j] = 0.f;

    for (int k0 = 0; k0 < 128; k0 += 32) {
        #pragma unroll
        for (int u = 0; u < 2; u++) {
            int ff = tid * 2 + u;
            int r = ff >> 3, c = (ff & 7) * 4;
            float4 v = make_float4(0.f, 0.f, 0.f, 0.f);
            int gr = rowBase + r;
            if (gr < N) v = *(const float4*)(x + (size_t)gr * 128 + k0 + c);
            As[r][c] = v.x; As[r][c + 1] = v.y; As[r][c + 2] = v.z; As[r][c + 3] = v.w;
        }
        #pragma unroll
        for (int u = 0; u < 4; u++) {
            int ff = tid + u * 256;
            int r = ff >> 5, c = (ff & 31) * 4;
            *(float4*)&Bs[r][c] = *(const float4*)(W + (size_t)(k0 + r) * 128 + c);
        }
        __syncthreads();
        #pragma unroll
        for (int kk = 0; kk < 32; kk++) {
            float aa[4];
            #pragma unroll
            for (int i = 0; i < 4; i++) aa[i] = As[ty * 4 + i][kk];
            float4 b0 = *(float4*)&Bs[kk][tx * 8];
            float4 b1 = *(float4*)&Bs[kk][tx * 8 + 4];
            float bb[8] = {b0.x, b0.y, b0.z, b0.w, b1.x, b1.y, b1.z, b1.w};
            #pragma unroll
            for (int i = 0; i < 4; i++)
                #pragma unroll
                for (int j = 0; j < 8; j++) acc[i][j] = fmaf(aa[i], bb[j], acc[i][j]);
        }
        __syncthreads();
    }
    int head = tx >> 2, sub = tx & 3;
    float wsv[8], wdv[8];
    #pragma unroll
    for (int j = 0; j < 8; j++) {
        wsv[j] = a_src[head * 32 + sub * 8 + j];
        wdv[j] = a_dst[head * 32 + sub * 8 + j];
    }
    #pragma unroll
    for (int i = 0; i < 4; i++) {
        int gr = rowBase + ty * 4 + i;
        float ps = 0.f, pd = 0.f;
        #pragma unroll
        for (int j = 0; j < 8; j++) { ps = fmaf(acc[i][j], wsv[j], ps); pd = fmaf(acc[i][j], wdv[j], pd); }
        ps += __shfl_xor(ps, 1); ps += __shfl_xor(ps, 2);
        pd += __shfl_xor(pd, 1); pd += __shfl_xor(pd, 2);
        if (gr < N) {
            *(float4*)(h1 + (size_t)gr * 128 + tx * 8) =
                make_float4(acc[i][0], acc[i][1], acc[i][2], acc[i][3]);
            *(float4*)(h1 + (size_t)gr * 128 + tx * 8 + 4) =
                make_float4(acc[i][4], acc[i][5], acc[i][6], acc[i][7]);
            if (sub == 0) { as1[gr * 4 + head] = ps; ad1[gr * 4 + head] = pd; }
        }
    }
}

// ---------------------------------------------------------------- agg1: wave per node, online softmax, 128 ch
__global__ __launch_bounds__(256) void agg1_kernel(
    const float* __restrict__ h1, const float* __restrict__ as1, const float* __restrict__ ad1,
    const int* __restrict__ rowptr, const int* __restrict__ csr_src,
    const float* __restrict__ b1, const float* __restrict__ bn_g, const float* __restrict__ bn_b,
    const float* __restrict__ bn_m, const float* __restrict__ bn_v,
    float* __restrict__ h1p, int N) {
    int wid = (int)((blockIdx.x * blockDim.x + threadIdx.x) >> 6);
    if (wid >= N) return;
    int lane = threadIdx.x & 63;
    int n = wid;
    int hl = lane >> 4;              // head of channels lane*2, lane*2+1
    float ad = ad1[n * 4 + hl];
    int beg = rowptr[n], end = rowptr[n + 1];
    float m = -INFINITY, ssum = 0.f, acc0 = 0.f, acc1 = 0.f;
    for (int idx = beg; idx <= end; idx++) {   // idx==end -> self loop
        int s = (idx < end) ? csr_src[idx] : n;
        float val = as1[s * 4 + hl] + ad;
        val = (val >= 0.f) ? val : NEG_SLOPE * val;
        float newm = fmaxf(m, val);
        float scale = __expf(m - newm);        // exp(-inf)=0 on first iter
        float p = __expf(val - newm);
        float2 hv = *(const float2*)(h1 + (size_t)s * 128 + lane * 2);
        acc0 = acc0 * scale + p * hv.x;
        acc1 = acc1 * scale + p * hv.y;
        ssum = ssum * scale + p;
        m = newm;
    }
    float inv = 1.f / ssum;
    int c0 = lane * 2;
    float o[2] = {acc0 * inv, acc1 * inv};
    #pragma unroll
    for (int u = 0; u < 2; u++) {
        int c = c0 + u;
        float v = o[u] + b1[c];
        v = (v - bn_m[c]) * rsqrtf(bn_v[c] + BN_EPS) * bn_g[c] + bn_b[c];
        o[u] = (v > 0.f) ? v : expm1f(v);      // ELU
    }
    *(float2*)(h1p + (size_t)n * 128 + c0) = make_float2(o[0], o[1]);
}

// ---------------------------------------------------------------- GEMM2: h2 = h1p @ W2 (+ scalar alpha epilogue)
// h1p:[N,128], W2:[128,32] -> h2:[N,32]; as2/ad2:[N]
__global__ __launch_bounds__(256) void gemm2_kernel(
    const float* __restrict__ A, const float* __restrict__ W,
    const float* __restrict__ a_src, const float* __restrict__ a_dst,
    float* __restrict__ h2, float* __restrict__ as2, float* __restrict__ ad2, int N) {
    __shared__ float As[64][33];
    __shared__ float Bs[32][32];
    int tid = threadIdx.x;
    int tx = tid & 31, ty = tid >> 5;
    int rowBase = blockIdx.x * 64;
    float acc[8];
    #pragma unroll
    for (int i = 0; i < 8; i++) acc[i] = 0.f;
    for (int k0 = 0; k0 < 128; k0 += 32) {
        #pragma unroll
        for (int u = 0; u < 2; u++) {
            int ff = tid * 2 + u;
            int r = ff >> 3, c = (ff & 7) * 4;
            float4 v = make_float4(0.f, 0.f, 0.f, 0.f);
            int gr = rowBase + r;
            if (gr < N) v = *(const float4*)(A + (size_t)gr * 128 + k0 + c);
            As[r][c] = v.x; As[r][c + 1] = v.y; As[r][c + 2] = v.z; As[r][c + 3] = v.w;
        }
        {
            int r = tid >> 3, c = (tid & 7) * 4;
            *(float4*)&Bs[r][c] = *(const float4*)(W + (size_t)(k0 + r) * 32 + c);
        }
        __syncthreads();
        #pragma unroll
        for (int kk = 0; kk < 32; kk++) {
            float b = Bs[kk][tx];
            #pragma unroll
            for (int i = 0; i < 8; i++) acc[i] = fmaf(As[ty * 8 + i][kk], b, acc[i]);
        }
        __syncthreads();
    }
    float aws = a_src[tx], awd = a_dst[tx];
    #pragma unroll
    for (int i = 0; i < 8; i++) {
        int gr = rowBase + ty * 8 + i;
        float v = acc[i];
        float ps = v * aws, pd = v * awd;
        #pragma unroll
        for (int off = 1; off < 32; off <<= 1) { ps += __shfl_xor(ps, off); pd += __shfl_xor(pd, off); }
        if (gr < N) {
            h2[(size_t)gr * 32 + tx] = v;
            if (tx == 0) { as2[gr] = ps; ad2[gr] = pd; }
        }
    }
}

// ---------------------------------------------------------------- agg2: 2 nodes per wave, 32 ch each
__global__ __launch_bounds__(256) void agg2_kernel(
    const float* __restrict__ h2, const float* __restrict__ as2, const float* __restrict__ ad2,
    const int* __restrict__ rowptr, const int* __restrict__ csr_src,
    const float* __restrict__ b2, float* __restrict__ hl2, int N) {
    int wid = (int)((blockIdx.x * blockDim.x + threadIdx.x) >> 6);
    int lane = threadIdx.x & 63;
    int half = lane >> 5;
    int c = lane & 31;
    int n = wid * 2 + half;
    bool valid = (n < N);
    int nc = valid ? n : (N - 1);
    float adv = ad2[nc];
    int beg = rowptr[nc], end = rowptr[nc + 1];
    float m = -INFINITY, ssum = 0.f, acc = 0.f;
    for (int idx = beg; idx <= end; idx++) {
        int s = (idx < end) ? csr_src[idx] : nc;
        float val = as2[s] + adv;
        val = (val >= 0.f) ? val : NEG_SLOPE * val;
        float newm = fmaxf(m, val);
        float scale = __expf(m - newm);
        float p = __expf(val - newm);
        float hv = h2[(size_t)s * 32 + c];
        acc = acc * scale + p * hv;
        ssum = ssum * scale + p;
        m = newm;
    }
    if (valid) hl2[(size_t)n * 32 + c] = acc / ssum + b2[c];
}

// ---------------------------------------------------------------- fused head: reasoner -> expl, decoder, classifier, log_softmax
__global__ __launch_bounds__(256) void head_kernel(
    const float* __restrict__ context, const float* __restrict__ hl2,
    const float* __restrict__ rw1, const float* __restrict__ rb1,
    const float* __restrict__ rw2, const float* __restrict__ rb2,
    const float* __restrict__ dw, const float* __restrict__ db,
    const float* __restrict__ cw, const float* __restrict__ cb,
    float* __restrict__ out_lsm, float* __restrict__ out_expl, int N) {
    __shared__ float s_rw1[192], s_rw2[1024], s_dw[1024], s_cw[320];
    __shared__ float s_rb1[32], s_rb2[32], s_db[32], s_cb[10];
    int tid = threadIdx.x;
    for (int i = tid; i < 192; i += 256) s_rw1[i] = rw1[i];
    for (int i = tid; i < 1024; i += 256) { s_rw2[i] = rw2[i]; s_dw[i] = dw[i]; }
    for (int i = tid; i < 320; i += 256) s_cw[i] = cw[i];
    if (tid < 32) { s_rb1[tid] = rb1[tid]; s_rb2[tid] = rb2[tid]; s_db[tid] = db[tid]; }
    if (tid < 10) s_cb[tid] = cb[tid];
    __syncthreads();
    int n = blockIdx.x * 256 + tid;
    if (n >= N) return;

    float ctx[6];
    #pragma unroll
    for (int i = 0; i < 6; i++) ctx[i] = context[(size_t)n * 6 + i];

    float t1[32];
    #pragma unroll
    for (int c = 0; c < 32; c++) t1[c] = s_rb1[c];
    #pragma unroll
    for (int i = 0; i < 6; i++) {
        float s = ctx[i];
        #pragma unroll
        for (int c = 0; c < 32; c++) t1[c] = fmaf(s, s_rw1[i * 32 + c], t1[c]);
    }
    #pragma unroll
    for (int c = 0; c < 32; c++) t1[c] = fmaxf(t1[c], 0.f);

    float ex[32];
    #pragma unroll
    for (int c = 0; c < 32; c++) ex[c] = s_rb2[c];
    #pragma unroll
    for (int c = 0; c < 32; c++) {
        float s = t1[c];
        #pragma unroll
        for (int c2 = 0; c2 < 32; c2++) ex[c2] = fmaf(s, s_rw2[c * 32 + c2], ex[c2]);
    }
    #pragma unroll
    for (int c = 0; c < 32; c += 4)
        *(float4*)(out_expl + (size_t)n * 32 + c) = make_float4(ex[c], ex[c + 1], ex[c + 2], ex[c + 3]);

    float rec[32];
    #pragma unroll
    for (int k = 0; k < 32; k++) rec[k] = s_db[k];
    #pragma unroll
    for (int c = 0; c < 32; c++) {
        float s = ex[c];
        #pragma unroll
        for (int k = 0; k < 32; k++) rec[k] = fmaf(s, s_dw[c * 32 + k], rec[k]);
    }
    float comb[32];
    #pragma unroll
    for (int k = 0; k < 32; k += 4) {
        float4 h = *(const float4*)(hl2 + (size_t)n * 32 + k);
        comb[k] = h.x + RECON_W * rec[k];
        comb[k + 1] = h.y + RECON_W * rec[k + 1];
        comb[k + 2] = h.z + RECON_W * rec[k + 2];
        comb[k + 3] = h.w + RECON_W * rec[k + 3];
    }
    float lg[10];
    #pragma unroll
    for (int j = 0; j < 10; j++) lg[j] = s_cb[j];
    #pragma unroll
    for (int k = 0; k < 32; k++) {
        float s = comb[k];
        #pragma unroll
        for (int j = 0; j < 10; j++) lg[j] = fmaf(s, s_cw[k * 10 + j], lg[j]);
    }
    float mx = lg[0];
    #pragma unroll
    for (int j = 1; j < 10; j++) mx = fmaxf(mx, lg[j]);
    float se = 0.f;
    #pragma unroll
    for (int j = 0; j < 10; j++) se += expf(lg[j] - mx);
    float lse = mx + logf(se);
    #pragma unroll
    for (int j = 0; j < 10; j++) out_lsm[(size_t)n * 10 + j] = lg[j] - lse;
}

// ---------------------------------------------------------------- launch
extern "C" void kernel_launch(void* const* d_in, const int* in_sizes, int n_in,
                              void* d_out, int out_size, void* d_ws, size_t ws_size,
                              hipStream_t stream) {
    const float* x    = (const float*)d_in[0];
    const int* ei     = (const int*)d_in[1];
    const float* ctx  = (const float*)d_in[2];
    const float* W1   = (const float*)d_in[3];
    const float* a_s1 = (const float*)d_in[4];
    const float* a_d1 = (const float*)d_in[5];
    const float* b1   = (const float*)d_in[6];
    const float* bn_g = (const float*)d_in[7];
    const float* bn_b = (const float*)d_in[8];
    const float* bn_m = (const float*)d_in[9];
    const float* bn_v = (const float*)d_in[10];
    const float* W2   = (const float*)d_in[11];
    const float* a_s2 = (const float*)d_in[12];
    const float* a_d2 = (const float*)d_in[13];
    const float* b2   = (const float*)d_in[14];
    const float* rw1  = (const float*)d_in[15];
    const float* rb1  = (const float*)d_in[16];
    const float* rw2  = (const float*)d_in[17];
    const float* rb2  = (const float*)d_in[18];
    const float* dw   = (const float*)d_in[19];
    const float* db   = (const float*)d_in[20];
    const float* cw   = (const float*)d_in[21];
    const float* cb   = (const float*)d_in[22];

    int N = in_sizes[0] / 128;
    int E = in_sizes[1] / 2;
    const int* esrc = ei;
    const int* edst = ei + E;

    char* w = (char*)d_ws;
    auto alloc = [&](size_t bytes) {
        void* p = (void*)w;
        w += (bytes + 255) & ~(size_t)255;
        return p;
    };
    float* h1   = (float*)alloc((size_t)N * 128 * 4);
    float* h1p  = (float*)alloc((size_t)N * 128 * 4);
    float* h2   = (float*)alloc((size_t)N * 32 * 4);
    float* hl2  = (float*)alloc((size_t)N * 32 * 4);
    float* as1  = (float*)alloc((size_t)N * 4 * 4);
    float* ad1  = (float*)alloc((size_t)N * 4 * 4);
    float* as2  = (float*)alloc((size_t)N * 4);
    float* ad2  = (float*)alloc((size_t)N * 4);
    int* deg    = (int*)alloc((size_t)N * 4);
    int* rowptr = (int*)alloc((size_t)(N + 1) * 4);
    int* cursor = (int*)alloc((size_t)N * 4);
    int* csrS   = (int*)alloc((size_t)E * 4);

    float* out0 = (float*)d_out;            // log_softmax [N,10]
    float* out1 = out0 + (size_t)N * 10;    // expl [N,32]

    hipMemsetAsync(deg, 0, (size_t)N * 4, stream);
    hipMemsetAsync(cursor, 0, (size_t)N * 4, stream);

    count_kernel<<<(E + 255) / 256, 256, 0, stream>>>(edst, E, deg);
    scan_kernel<<<1, 1024, 0, stream>>>(deg, rowptr, N);
    scatter_kernel<<<(E + 255) / 256, 256, 0, stream>>>(esrc, edst, E, rowptr, cursor, csrS);

    gemm1_kernel<<<(N + 63) / 64, 256, 0, stream>>>(x, W1, a_s1, a_d1, h1, as1, ad1, N);
    agg1_kernel<<<(N + 3) / 4, 256, 0, stream>>>(h1, as1, ad1, rowptr, csrS,
                                                 b1, bn_g, bn_b, bn_m, bn_v, h1p, N);
    gemm2_kernel<<<(N + 63) / 64, 256, 0, stream>>>(h1p, W2, a_s2, a_d2, h2, as2, ad2, N);
    agg2_kernel<<<(N + 7) / 8, 256, 0, stream>>>(h2, as2, ad2, rowptr, csrS, b2, hl2, N);
    head_kernel<<<(N + 255) / 256, 256, 0, stream>>>(ctx, hl2, rw1, rb1, rw2, rb2,
                                                     dw, db, cw, cb, out0, out1, N);
}

// Round 2
// 494.225 us; speedup vs baseline: 1.1928x; 1.1928x over previous
//
#include <hip/hip_runtime.h>
#include <hip/hip_bf16.h>
#include <math.h>

#define NEG_SLOPE 0.2f
#define RECON_W 0.1f
#define BN_EPS 1e-5f

__device__ __forceinline__ float lrelu(float v) {
    return (v >= 0.f) ? v : NEG_SLOPE * v;
}

// ---------------------------------------------------------------- CSR build
__global__ void count_kernel(const int* __restrict__ dst, int E, int* __restrict__ deg) {
    int e = blockIdx.x * blockDim.x + threadIdx.x;
    if (e < E) atomicAdd(&deg[dst[e]], 1);
}

// single-block scan, int4-vectorized (4096 elements / iteration)
__global__ __launch_bounds__(1024) void scan_kernel(const int* __restrict__ deg,
                                                    int* __restrict__ rowptr, int N) {
    __shared__ int wsum[16];
    __shared__ int s_tot;
    int tid = threadIdx.x;
    int lane = tid & 63;
    int w = tid >> 6;
    int running = 0;
    for (int base = 0; base < N; base += 4096) {
        int i0 = base + tid * 4;
        int4 v4 = make_int4(0, 0, 0, 0);
        if (i0 + 3 < N) {
            v4 = *(const int4*)(deg + i0);
        } else {
            if (i0 < N) v4.x = deg[i0];
            if (i0 + 1 < N) v4.y = deg[i0 + 1];
            if (i0 + 2 < N) v4.z = deg[i0 + 2];
            if (i0 + 3 < N) v4.w = deg[i0 + 3];
        }
        int v = v4.x + v4.y + v4.z + v4.w;
        int inc = v;
        #pragma unroll
        for (int off = 1; off < 64; off <<= 1) {
            int t = __shfl_up(inc, off);
            if (lane >= off) inc += t;
        }
        if (lane == 63) wsum[w] = inc;
        __syncthreads();
        if (tid == 0) {
            int r = 0;
            #pragma unroll
            for (int j = 0; j < 16; j++) { int t = wsum[j]; wsum[j] = r; r += t; }
            s_tot = r;
        }
        __syncthreads();
        int excl = running + wsum[w] + inc - v;
        if (i0 + 3 < N) {
            *(int4*)(rowptr + i0) = make_int4(excl, excl + v4.x, excl + v4.x + v4.y,
                                              excl + v4.x + v4.y + v4.z);
        } else {
            if (i0 < N) rowptr[i0] = excl;
            if (i0 + 1 < N) rowptr[i0 + 1] = excl + v4.x;
            if (i0 + 2 < N) rowptr[i0 + 2] = excl + v4.x + v4.y;
            if (i0 + 3 < N) rowptr[i0 + 3] = excl + v4.x + v4.y + v4.z;
        }
        running += s_tot;
        __syncthreads();
    }
    if (tid == 0) rowptr[N] = running;
}

// scatter + layer-1 edge weights (runs AFTER gemm1: needs as1/ad1)
__global__ void scatter_kernel(const int* __restrict__ src, const int* __restrict__ dst, int E,
                               const int* __restrict__ rowptr, int* __restrict__ cursor,
                               int* __restrict__ csrS, int* __restrict__ csrD,
                               float* __restrict__ csrW,
                               const float* __restrict__ as1, const float* __restrict__ ad1) {
    int e = blockIdx.x * blockDim.x + threadIdx.x;
    if (e >= E) return;
    int s = src[e], d = dst[e];
    int pos = rowptr[d] + atomicAdd(&cursor[d], 1);
    csrS[pos] = s;
    csrD[pos] = d;
    float4 av = *(const float4*)(as1 + (size_t)s * 4);
    float4 bv = *(const float4*)(ad1 + (size_t)d * 4);
    float4 wv;
    wv.x = __expf(lrelu(av.x + bv.x));
    wv.y = __expf(lrelu(av.y + bv.y));
    wv.z = __expf(lrelu(av.z + bv.z));
    wv.w = __expf(lrelu(av.w + bv.w));
    *(float4*)(csrW + (size_t)pos * 4) = wv;
}

// layer-2 edge weights (after gemm2), coalesced over csr positions
__global__ void weight2_kernel(const int* __restrict__ csrS, const int* __restrict__ csrD, int E,
                               const float* __restrict__ as2, const float* __restrict__ ad2,
                               float* __restrict__ w2) {
    int e = blockIdx.x * blockDim.x + threadIdx.x;
    if (e >= E) return;
    float v = as2[csrS[e]] + ad2[csrD[e]];
    w2[e] = __expf(lrelu(v));
}

// ---------------------------------------------------------------- GEMM1: h1 = x @ W1 (+ alpha epilogue)
__global__ __launch_bounds__(256) void gemm1_kernel(
    const float* __restrict__ x, const float* __restrict__ W,
    const float* __restrict__ a_src, const float* __restrict__ a_dst,
    float* __restrict__ h1, float* __restrict__ as1, float* __restrict__ ad1, int N) {
    __shared__ float As[64][33];
    __shared__ float Bs[32][128];
    int tid = threadIdx.x;
    int tx = tid & 15;
    int ty = tid >> 4;
    int rowBase = blockIdx.x * 64;
    float acc[4][8];
    #pragma unroll
    for (int i = 0; i < 4; i++)
        #pragma unroll
        for (int j = 0; j < 8; j++) acc[i][j] = 0.f;

    for (int k0 = 0; k0 < 128; k0 += 32) {
        #pragma unroll
        for (int u = 0; u < 2; u++) {
            int ff = tid * 2 + u;
            int r = ff >> 3, c = (ff & 7) * 4;
            float4 v = make_float4(0.f, 0.f, 0.f, 0.f);
            int gr = rowBase + r;
            if (gr < N) v = *(const float4*)(x + (size_t)gr * 128 + k0 + c);
            As[r][c] = v.x; As[r][c + 1] = v.y; As[r][c + 2] = v.z; As[r][c + 3] = v.w;
        }
        #pragma unroll
        for (int u = 0; u < 4; u++) {
            int ff = tid + u * 256;
            int r = ff >> 5, c = (ff & 31) * 4;
            *(float4*)&Bs[r][c] = *(const float4*)(W + (size_t)(k0 + r) * 128 + c);
        }
        __syncthreads();
        #pragma unroll
        for (int kk = 0; kk < 32; kk++) {
            float aa[4];
            #pragma unroll
            for (int i = 0; i < 4; i++) aa[i] = As[ty * 4 + i][kk];
            float4 b0 = *(float4*)&Bs[kk][tx * 8];
            float4 b1 = *(float4*)&Bs[kk][tx * 8 + 4];
            float bb[8] = {b0.x, b0.y, b0.z, b0.w, b1.x, b1.y, b1.z, b1.w};
            #pragma unroll
            for (int i = 0; i < 4; i++)
                #pragma unroll
                for (int j = 0; j < 8; j++) acc[i][j] = fmaf(aa[i], bb[j], acc[i][j]);
        }
        __syncthreads();
    }
    int head = tx >> 2, sub = tx & 3;
    float wsv[8], wdv[8];
    #pragma unroll
    for (int j = 0; j < 8; j++) {
        wsv[j] = a_src[head * 32 + sub * 8 + j];
        wdv[j] = a_dst[head * 32 + sub * 8 + j];
    }
    #pragma unroll
    for (int i = 0; i < 4; i++) {
        int gr = rowBase + ty * 4 + i;
        float ps = 0.f, pd = 0.f;
        #pragma unroll
        for (int j = 0; j < 8; j++) { ps = fmaf(acc[i][j], wsv[j], ps); pd = fmaf(acc[i][j], wdv[j], pd); }
        ps += __shfl_xor(ps, 1); ps += __shfl_xor(ps, 2);
        pd += __shfl_xor(pd, 1); pd += __shfl_xor(pd, 2);
        if (gr < N) {
            *(float4*)(h1 + (size_t)gr * 128 + tx * 8) =
                make_float4(acc[i][0], acc[i][1], acc[i][2], acc[i][3]);
            *(float4*)(h1 + (size_t)gr * 128 + tx * 8 + 4) =
                make_float4(acc[i][4], acc[i][5], acc[i][6], acc[i][7]);
            if (sub == 0) { as1[gr * 4 + head] = ps; ad1[gr * 4 + head] = pd; }
        }
    }
}

// ---------------------------------------------------------------- agg1: wave per node, precomputed weights, unroll x2
__global__ __launch_bounds__(256) void agg1_kernel(
    const float* __restrict__ h1, const float* __restrict__ as1, const float* __restrict__ ad1,
    const int* __restrict__ rowptr, const int* __restrict__ csrS, const float* __restrict__ csrW,
    const float* __restrict__ b1, const float* __restrict__ bn_g, const float* __restrict__ bn_b,
    const float* __restrict__ bn_m, const float* __restrict__ bn_v,
    float* __restrict__ h1p, int N) {
    int n = (int)((blockIdx.x * blockDim.x + threadIdx.x) >> 6);
    if (n >= N) return;
    int lane = threadIdx.x & 63;
    int hl = lane >> 4;
    int c0 = lane * 2;

    // self loop
    float aself = lrelu(as1[n * 4 + hl] + ad1[n * 4 + hl]);
    float wself = __expf(aself);
    float2 hs = *(const float2*)(h1 + (size_t)n * 128 + c0);
    float accA0 = wself * hs.x, accA1 = wself * hs.y, ssA = wself;
    float accB0 = 0.f, accB1 = 0.f, ssB = 0.f;

    int beg = rowptr[n], end = rowptr[n + 1];
    int idx = beg;
    for (; idx + 1 < end; idx += 2) {
        int s0 = csrS[idx], s1 = csrS[idx + 1];
        float p0 = csrW[idx * 4 + hl];
        float p1 = csrW[(idx + 1) * 4 + hl];
        float2 h0 = *(const float2*)(h1 + (size_t)s0 * 128 + c0);
        float2 h1v = *(const float2*)(h1 + (size_t)s1 * 128 + c0);
        accA0 = fmaf(p0, h0.x, accA0); accA1 = fmaf(p0, h0.y, accA1); ssA += p0;
        accB0 = fmaf(p1, h1v.x, accB0); accB1 = fmaf(p1, h1v.y, accB1); ssB += p1;
    }
    if (idx < end) {
        int s0 = csrS[idx];
        float p0 = csrW[idx * 4 + hl];
        float2 h0 = *(const float2*)(h1 + (size_t)s0 * 128 + c0);
        accA0 = fmaf(p0, h0.x, accA0); accA1 = fmaf(p0, h0.y, accA1); ssA += p0;
    }
    float inv = 1.f / (ssA + ssB);
    float o[2] = {(accA0 + accB0) * inv, (accA1 + accB1) * inv};
    #pragma unroll
    for (int u = 0; u < 2; u++) {
        int c = c0 + u;
        float v = o[u] + b1[c];
        v = (v - bn_m[c]) * rsqrtf(bn_v[c] + BN_EPS) * bn_g[c] + bn_b[c];
        o[u] = (v > 0.f) ? v : expm1f(v);
    }
    *(float2*)(h1p + (size_t)n * 128 + c0) = make_float2(o[0], o[1]);
}

// ---------------------------------------------------------------- GEMM2: h2 = h1p @ W2 (+ scalar alpha epilogue)
__global__ __launch_bounds__(256) void gemm2_kernel(
    const float* __restrict__ A, const float* __restrict__ W,
    const float* __restrict__ a_src, const float* __restrict__ a_dst,
    float* __restrict__ h2, float* __restrict__ as2, float* __restrict__ ad2, int N) {
    __shared__ float As[64][33];
    __shared__ float Bs[32][32];
    int tid = threadIdx.x;
    int tx = tid & 31, ty = tid >> 5;
    int rowBase = blockIdx.x * 64;
    float acc[8];
    #pragma unroll
    for (int i = 0; i < 8; i++) acc[i] = 0.f;
    for (int k0 = 0; k0 < 128; k0 += 32) {
        #pragma unroll
        for (int u = 0; u < 2; u++) {
            int ff = tid * 2 + u;
            int r = ff >> 3, c = (ff & 7) * 4;
            float4 v = make_float4(0.f, 0.f, 0.f, 0.f);
            int gr = rowBase + r;
            if (gr < N) v = *(const float4*)(A + (size_t)gr * 128 + k0 + c);
            As[r][c] = v.x; As[r][c + 1] = v.y; As[r][c + 2] = v.z; As[r][c + 3] = v.w;
        }
        {
            int r = tid >> 3, c = (tid & 7) * 4;
            *(float4*)&Bs[r][c] = *(const float4*)(W + (size_t)(k0 + r) * 32 + c);
        }
        __syncthreads();
        #pragma unroll
        for (int kk = 0; kk < 32; kk++) {
            float b = Bs[kk][tx];
            #pragma unroll
            for (int i = 0; i < 8; i++) acc[i] = fmaf(As[ty * 8 + i][kk], b, acc[i]);
        }
        __syncthreads();
    }
    float aws = a_src[tx], awd = a_dst[tx];
    #pragma unroll
    for (int i = 0; i < 8; i++) {
        int gr = rowBase + ty * 8 + i;
        float v = acc[i];
        float ps = v * aws, pd = v * awd;
        #pragma unroll
        for (int off = 1; off < 32; off <<= 1) { ps += __shfl_xor(ps, off); pd += __shfl_xor(pd, off); }
        if (gr < N) {
            h2[(size_t)gr * 32 + tx] = v;
            if (tx == 0) { as2[gr] = ps; ad2[gr] = pd; }
        }
    }
}

// ---------------------------------------------------------------- agg2: 2 nodes/wave, precomputed weights, unroll x2
__global__ __launch_bounds__(256) void agg2_kernel(
    const float* __restrict__ h2, const float* __restrict__ as2, const float* __restrict__ ad2,
    const int* __restrict__ rowptr, const int* __restrict__ csrS, const float* __restrict__ w2,
    const float* __restrict__ b2, float* __restrict__ hl2, int N) {
    int wid = (int)((blockIdx.x * blockDim.x + threadIdx.x) >> 6);
    int lane = threadIdx.x & 63;
    int half = lane >> 5;
    int c = lane & 31;
    int n = wid * 2 + half;
    bool valid = (n < N);
    int nc = valid ? n : (N - 1);

    float aself = lrelu(as2[nc] + ad2[nc]);
    float ws = __expf(aself);
    float hs = h2[(size_t)nc * 32 + c];
    float accA = ws * hs, ssA = ws, accB = 0.f, ssB = 0.f;

    int beg = rowptr[nc], end = rowptr[nc + 1];
    int idx = beg;
    for (; idx + 1 < end; idx += 2) {
        int s0 = csrS[idx], s1 = csrS[idx + 1];
        float p0 = w2[idx], p1 = w2[idx + 1];
        float v0 = h2[(size_t)s0 * 32 + c];
        float v1 = h2[(size_t)s1 * 32 + c];
        accA = fmaf(p0, v0, accA); ssA += p0;
        accB = fmaf(p1, v1, accB); ssB += p1;
    }
    if (idx < end) {
        int s0 = csrS[idx];
        float p0 = w2[idx];
        float v0 = h2[(size_t)s0 * 32 + c];
        accA = fmaf(p0, v0, accA); ssA += p0;
    }
    if (valid) hl2[(size_t)n * 32 + c] = (accA + accB) / (ssA + ssB) + b2[c];
}

// ---------------------------------------------------------------- fused head
__global__ __launch_bounds__(256) void head_kernel(
    const float* __restrict__ context, const float* __restrict__ hl2,
    const float* __restrict__ rw1, const float* __restrict__ rb1,
    const float* __restrict__ rw2, const float* __restrict__ rb2,
    const float* __restrict__ dw, const float* __restrict__ db,
    const float* __restrict__ cw, const float* __restrict__ cb,
    float* __restrict__ out_lsm, float* __restrict__ out_expl, int N) {
    __shared__ float s_rw1[192], s_rw2[1024], s_dw[1024], s_cw[320];
    __shared__ float s_rb1[32], s_rb2[32], s_db[32], s_cb[10];
    int tid = threadIdx.x;
    for (int i = tid; i < 192; i += 256) s_rw1[i] = rw1[i];
    for (int i = tid; i < 1024; i += 256) { s_rw2[i] = rw2[i]; s_dw[i] = dw[i]; }
    for (int i = tid; i < 320; i += 256) s_cw[i] = cw[i];
    if (tid < 32) { s_rb1[tid] = rb1[tid]; s_rb2[tid] = rb2[tid]; s_db[tid] = db[tid]; }
    if (tid < 10) s_cb[tid] = cb[tid];
    __syncthreads();
    int n = blockIdx.x * 256 + tid;
    if (n >= N) return;

    float ctx[6];
    #pragma unroll
    for (int i = 0; i < 6; i++) ctx[i] = context[(size_t)n * 6 + i];

    float t1[32];
    #pragma unroll
    for (int c = 0; c < 32; c++) t1[c] = s_rb1[c];
    #pragma unroll
    for (int i = 0; i < 6; i++) {
        float s = ctx[i];
        #pragma unroll
        for (int c = 0; c < 32; c++) t1[c] = fmaf(s, s_rw1[i * 32 + c], t1[c]);
    }
    #pragma unroll
    for (int c = 0; c < 32; c++) t1[c] = fmaxf(t1[c], 0.f);

    float ex[32];
    #pragma unroll
    for (int c = 0; c < 32; c++) ex[c] = s_rb2[c];
    #pragma unroll
    for (int c = 0; c < 32; c++) {
        float s = t1[c];
        #pragma unroll
        for (int c2 = 0; c2 < 32; c2++) ex[c2] = fmaf(s, s_rw2[c * 32 + c2], ex[c2]);
    }
    #pragma unroll
    for (int c = 0; c < 32; c += 4)
        *(float4*)(out_expl + (size_t)n * 32 + c) = make_float4(ex[c], ex[c + 1], ex[c + 2], ex[c + 3]);

    float rec[32];
    #pragma unroll
    for (int k = 0; k < 32; k++) rec[k] = s_db[k];
    #pragma unroll
    for (int c = 0; c < 32; c++) {
        float s = ex[c];
        #pragma unroll
        for (int k = 0; k < 32; k++) rec[k] = fmaf(s, s_dw[c * 32 + k], rec[k]);
    }
    float comb[32];
    #pragma unroll
    for (int k = 0; k < 32; k += 4) {
        float4 h = *(const float4*)(hl2 + (size_t)n * 32 + k);
        comb[k] = h.x + RECON_W * rec[k];
        comb[k + 1] = h.y + RECON_W * rec[k + 1];
        comb[k + 2] = h.z + RECON_W * rec[k + 2];
        comb[k + 3] = h.w + RECON_W * rec[k + 3];
    }
    float lg[10];
    #pragma unroll
    for (int j = 0; j < 10; j++) lg[j] = s_cb[j];
    #pragma unroll
    for (int k = 0; k < 32; k++) {
        float s = comb[k];
        #pragma unroll
        for (int j = 0; j < 10; j++) lg[j] = fmaf(s, s_cw[k * 10 + j], lg[j]);
    }
    float mx = lg[0];
    #pragma unroll
    for (int j = 1; j < 10; j++) mx = fmaxf(mx, lg[j]);
    float se = 0.f;
    #pragma unroll
    for (int j = 0; j < 10; j++) se += expf(lg[j] - mx);
    float lse = mx + logf(se);
    #pragma unroll
    for (int j = 0; j < 10; j++) out_lsm[(size_t)n * 10 + j] = lg[j] - lse;
}

// ---------------------------------------------------------------- launch
extern "C" void kernel_launch(void* const* d_in, const int* in_sizes, int n_in,
                              void* d_out, int out_size, void* d_ws, size_t ws_size,
                              hipStream_t stream) {
    const float* x    = (const float*)d_in[0];
    const int* ei     = (const int*)d_in[1];
    const float* ctx  = (const float*)d_in[2];
    const float* W1   = (const float*)d_in[3];
    const float* a_s1 = (const float*)d_in[4];
    const float* a_d1 = (const float*)d_in[5];
    const float* b1   = (const float*)d_in[6];
    const float* bn_g = (const float*)d_in[7];
    const float* bn_b = (const float*)d_in[8];
    const float* bn_m = (const float*)d_in[9];
    const float* bn_v = (const float*)d_in[10];
    const float* W2   = (const float*)d_in[11];
    const float* a_s2 = (const float*)d_in[12];
    const float* a_d2 = (const float*)d_in[13];
    const float* b2   = (const float*)d_in[14];
    const float* rw1  = (const float*)d_in[15];
    const float* rb1  = (const float*)d_in[16];
    const float* rw2  = (const float*)d_in[17];
    const float* rb2  = (const float*)d_in[18];
    const float* dw   = (const float*)d_in[19];
    const float* db   = (const float*)d_in[20];
    const float* cw   = (const float*)d_in[21];
    const float* cb   = (const float*)d_in[22];

    int N = in_sizes[0] / 128;
    int E = in_sizes[1] / 2;
    const int* esrc = ei;
    const int* edst = ei + E;

    char* w = (char*)d_ws;
    auto alloc = [&](size_t bytes) {
        void* p = (void*)w;
        w += (bytes + 255) & ~(size_t)255;
        return p;
    };
    float* h1   = (float*)alloc((size_t)N * 128 * 4);   // dead after agg1 -> reused below
    float* h1p  = (float*)alloc((size_t)N * 128 * 4);
    float* as1  = (float*)alloc((size_t)N * 4 * 4);
    float* ad1  = (float*)alloc((size_t)N * 4 * 4);
    float* as2  = (float*)alloc((size_t)N * 4);
    float* ad2  = (float*)alloc((size_t)N * 4);
    int* deg    = (int*)alloc((size_t)N * 2 * 4);       // deg + cursor adjacent, one memset
    int* cursor = deg + N;
    int* rowptr = (int*)alloc((size_t)(N + 1) * 4);
    int* csrS   = (int*)alloc((size_t)E * 4);
    int* csrD   = (int*)alloc((size_t)E * 4);
    float* csrW = (float*)alloc((size_t)E * 4 * 4);
    // alias the dead h1 region after agg1 (h2+hl2+w2 = 28.8MB < 51.2MB)
    float* h2   = h1;
    float* hl2  = h1 + (size_t)N * 32;
    float* w2   = h1 + (size_t)N * 64;

    float* out0 = (float*)d_out;            // log_softmax [N,10]
    float* out1 = out0 + (size_t)N * 10;    // expl [N,32]

    hipMemsetAsync(deg, 0, (size_t)N * 2 * 4, stream);

    count_kernel<<<(E + 255) / 256, 256, 0, stream>>>(edst, E, deg);
    scan_kernel<<<1, 1024, 0, stream>>>(deg, rowptr, N);
    gemm1_kernel<<<(N + 63) / 64, 256, 0, stream>>>(x, W1, a_s1, a_d1, h1p /*tmp? no*/, as1, ad1, N);
    // NOTE: gemm1 writes h1 features; keep them in a buffer that is NOT aliased (h1p is layer-1 output).
    // We wrote into h1p above by mistake? No: gemm1's output must live until agg1 reads it. Use h1p as
    // the raw feature buffer and write agg1's result into... — to keep aliasing sound we swap roles:
    //   rawH = h1p (gemm1 output), actH = csr-safe separate buffer.
    // agg1 reads rawH, writes actH = h1 region? But h1 region is reused for h2/hl2/w2 AFTER gemm2 reads actH.
    // Conflict: gemm2 reads actH (h1 region) while writing h2 (same region). So instead:
    //   gemm1 -> h1p (raw), agg1: h1p -> h1 (activated), gemm2 reads h1 writes h2... h2 aliases h1. BAD.
    // Simplest sound layout: gemm1 -> h1 (raw), agg1: h1 -> h1p (activated), gemm2 reads h1p,
    // h2/hl2/w2 alias h1 (dead after agg1). That is the original plan; fix the call below.
    scatter_kernel<<<(E + 255) / 256, 256, 0, stream>>>(esrc, edst, E, rowptr, cursor,
                                                        csrS, csrD, csrW, as1, ad1);
    agg1_kernel<<<(N + 3) / 4, 256, 0, stream>>>(h1p, as1, ad1, rowptr, csrS, csrW,
                                                 b1, bn_g, bn_b, bn_m, bn_v, h1, N);
    // h1 now holds activated layer-1 output; h1p is dead -> alias h2/hl2/w2 into h1p instead.
    h2  = h1p;
    hl2 = h1p + (size_t)N * 32;
    w2  = h1p + (size_t)N * 64;
    gemm2_kernel<<<(N + 63) / 64, 256, 0, stream>>>(h1, W2, a_s2, a_d2, h2, as2, ad2, N);
    weight2_kernel<<<(E + 255) / 256, 256, 0, stream>>>(csrS, csrD, E, as2, ad2, w2);
    agg2_kernel<<<(N + 7) / 8, 256, 0, stream>>>(h2, as2, ad2, rowptr, csrS, w2, b2, hl2, N);
    head_kernel<<<(N + 255) / 256, 256, 0, stream>>>(ctx, hl2, rw1, rb1, rw2, rb2,
                                                     dw, db, cw, cb, out0, out1, N);
}

// Round 3
// 487.002 us; speedup vs baseline: 1.2105x; 1.0148x over previous
//
#include <hip/hip_runtime.h>
#include <hip/hip_bf16.h>
#include <math.h>

#define NEG_SLOPE 0.2f
#define RECON_W 0.1f
#define BN_EPS 1e-5f

__device__ __forceinline__ float lrelu(float v) {
    return (v >= 0.f) ? v : NEG_SLOPE * v;
}
// fp32 -> bf16 (round-to-nearest-even, finite inputs)
__device__ __forceinline__ unsigned short f2bf(float f) {
    unsigned int u = __float_as_uint(f);
    u = (u + 0x7fffu + ((u >> 16) & 1u)) >> 16;
    return (unsigned short)u;
}
__device__ __forceinline__ float bf2f(unsigned short u) {
    return __uint_as_float(((unsigned int)u) << 16);
}
__device__ __forceinline__ unsigned int pack2bf(float a, float b) {
    return (unsigned int)f2bf(a) | ((unsigned int)f2bf(b) << 16);
}

// ---------------------------------------------------------------- CSR build
__global__ void count_kernel(const int* __restrict__ dst, int E, int* __restrict__ deg) {
    int e = blockIdx.x * blockDim.x + threadIdx.x;
    if (e < E) atomicAdd(&deg[dst[e]], 1);
}

// single-block scan, int4-vectorized (4096 elements / iteration)
__global__ __launch_bounds__(1024) void scan_kernel(const int* __restrict__ deg,
                                                    int* __restrict__ rowptr, int N) {
    __shared__ int wsum[16];
    __shared__ int s_tot;
    int tid = threadIdx.x;
    int lane = tid & 63;
    int w = tid >> 6;
    int running = 0;
    for (int base = 0; base < N; base += 4096) {
        int i0 = base + tid * 4;
        int4 v4 = make_int4(0, 0, 0, 0);
        if (i0 + 3 < N) {
            v4 = *(const int4*)(deg + i0);
        } else {
            if (i0 < N) v4.x = deg[i0];
            if (i0 + 1 < N) v4.y = deg[i0 + 1];
            if (i0 + 2 < N) v4.z = deg[i0 + 2];
            if (i0 + 3 < N) v4.w = deg[i0 + 3];
        }
        int v = v4.x + v4.y + v4.z + v4.w;
        int inc = v;
        #pragma unroll
        for (int off = 1; off < 64; off <<= 1) {
            int t = __shfl_up(inc, off);
            if (lane >= off) inc += t;
        }
        if (lane == 63) wsum[w] = inc;
        __syncthreads();
        if (tid == 0) {
            int r = 0;
            #pragma unroll
            for (int j = 0; j < 16; j++) { int t = wsum[j]; wsum[j] = r; r += t; }
            s_tot = r;
        }
        __syncthreads();
        int excl = running + wsum[w] + inc - v;
        if (i0 + 3 < N) {
            *(int4*)(rowptr + i0) = make_int4(excl, excl + v4.x, excl + v4.x + v4.y,
                                              excl + v4.x + v4.y + v4.z);
        } else {
            if (i0 < N) rowptr[i0] = excl;
            if (i0 + 1 < N) rowptr[i0 + 1] = excl + v4.x;
            if (i0 + 2 < N) rowptr[i0 + 2] = excl + v4.x + v4.y;
            if (i0 + 3 < N) rowptr[i0 + 3] = excl + v4.x + v4.y + v4.z;
        }
        running += s_tot;
        __syncthreads();
    }
    if (tid == 0) rowptr[N] = running;
}

// scatter: only int2{src,dst} per CSR slot (8B scattered write)
__global__ void scatter_kernel(const int* __restrict__ src, const int* __restrict__ dst, int E,
                               const int* __restrict__ rowptr, int* __restrict__ cursor,
                               int2* __restrict__ csrSD) {
    int e = blockIdx.x * blockDim.x + threadIdx.x;
    if (e >= E) return;
    int s = src[e], d = dst[e];
    int pos = rowptr[d] + atomicAdd(&cursor[d], 1);
    csrSD[pos] = make_int2(s, d);
}

// layer-1 edge weights, coalesced over CSR positions
__global__ void weight1_kernel(const int2* __restrict__ csrSD, int E,
                               const float* __restrict__ as1, const float* __restrict__ ad1,
                               float* __restrict__ csrW) {
    int e = blockIdx.x * blockDim.x + threadIdx.x;
    if (e >= E) return;
    int2 sd = csrSD[e];
    float4 av = *(const float4*)(as1 + (size_t)sd.x * 4);
    float4 bv = *(const float4*)(ad1 + (size_t)sd.y * 4);
    float4 wv;
    wv.x = __expf(lrelu(av.x + bv.x));
    wv.y = __expf(lrelu(av.y + bv.y));
    wv.z = __expf(lrelu(av.z + bv.z));
    wv.w = __expf(lrelu(av.w + bv.w));
    *(float4*)(csrW + (size_t)e * 4) = wv;
}

// layer-2 edge weights
__global__ void weight2_kernel(const int2* __restrict__ csrSD, int E,
                               const float* __restrict__ as2, const float* __restrict__ ad2,
                               float* __restrict__ w2) {
    int e = blockIdx.x * blockDim.x + threadIdx.x;
    if (e >= E) return;
    int2 sd = csrSD[e];
    w2[e] = __expf(lrelu(as2[sd.x] + ad2[sd.y]));
}

// ---------------------------------------------------------------- GEMM1: h1g(bf16) = x @ W1 (+ alpha epilogue)
__global__ __launch_bounds__(256) void gemm1_kernel(
    const float* __restrict__ x, const float* __restrict__ W,
    const float* __restrict__ a_src, const float* __restrict__ a_dst,
    unsigned short* __restrict__ h1g, float* __restrict__ as1, float* __restrict__ ad1, int N) {
    __shared__ float As[64][33];
    __shared__ float Bs[32][128];
    int tid = threadIdx.x;
    int tx = tid & 15;
    int ty = tid >> 4;
    int rowBase = blockIdx.x * 64;
    float acc[4][8];
    #pragma unroll
    for (int i = 0; i < 4; i++)
        #pragma unroll
        for (int j = 0; j < 8; j++) acc[i][j] = 0.f;

    for (int k0 = 0; k0 < 128; k0 += 32) {
        #pragma unroll
        for (int u = 0; u < 2; u++) {
            int ff = tid * 2 + u;
            int r = ff >> 3, c = (ff & 7) * 4;
            float4 v = make_float4(0.f, 0.f, 0.f, 0.f);
            int gr = rowBase + r;
            if (gr < N) v = *(const float4*)(x + (size_t)gr * 128 + k0 + c);
            As[r][c] = v.x; As[r][c + 1] = v.y; As[r][c + 2] = v.z; As[r][c + 3] = v.w;
        }
        #pragma unroll
        for (int u = 0; u < 4; u++) {
            int ff = tid + u * 256;
            int r = ff >> 5, c = (ff & 31) * 4;
            *(float4*)&Bs[r][c] = *(const float4*)(W + (size_t)(k0 + r) * 128 + c);
        }
        __syncthreads();
        #pragma unroll
        for (int kk = 0; kk < 32; kk++) {
            float aa[4];
            #pragma unroll
            for (int i = 0; i < 4; i++) aa[i] = As[ty * 4 + i][kk];
            float4 b0 = *(float4*)&Bs[kk][tx * 8];
            float4 b1 = *(float4*)&Bs[kk][tx * 8 + 4];
            float bb[8] = {b0.x, b0.y, b0.z, b0.w, b1.x, b1.y, b1.z, b1.w};
            #pragma unroll
            for (int i = 0; i < 4; i++)
                #pragma unroll
                for (int j = 0; j < 8; j++) acc[i][j] = fmaf(aa[i], bb[j], acc[i][j]);
        }
        __syncthreads();
    }
    int head = tx >> 2, sub = tx & 3;
    float wsv[8], wdv[8];
    #pragma unroll
    for (int j = 0; j < 8; j++) {
        wsv[j] = a_src[head * 32 + sub * 8 + j];
        wdv[j] = a_dst[head * 32 + sub * 8 + j];
    }
    #pragma unroll
    for (int i = 0; i < 4; i++) {
        int gr = rowBase + ty * 4 + i;
        float ps = 0.f, pd = 0.f;
        #pragma unroll
        for (int j = 0; j < 8; j++) { ps = fmaf(acc[i][j], wsv[j], ps); pd = fmaf(acc[i][j], wdv[j], pd); }
        ps += __shfl_xor(ps, 1); ps += __shfl_xor(ps, 2);
        pd += __shfl_xor(pd, 1); pd += __shfl_xor(pd, 2);
        if (gr < N) {
            uint4 pk;
            pk.x = pack2bf(acc[i][0], acc[i][1]);
            pk.y = pack2bf(acc[i][2], acc[i][3]);
            pk.z = pack2bf(acc[i][4], acc[i][5]);
            pk.w = pack2bf(acc[i][6], acc[i][7]);
            *(uint4*)(h1g + (size_t)gr * 128 + tx * 8) = pk;
            if (sub == 0) { as1[gr * 4 + head] = ps; ad1[gr * 4 + head] = pd; }
        }
    }
}

// ---------------------------------------------------------------- agg1: wave/node, bf16 gather (256B/row), unroll x2
__global__ __launch_bounds__(256) void agg1_kernel(
    const unsigned short* __restrict__ h1g,
    const float* __restrict__ as1, const float* __restrict__ ad1,
    const int* __restrict__ rowptr, const int2* __restrict__ csrSD, const float* __restrict__ csrW,
    const float* __restrict__ b1, const float* __restrict__ bn_g, const float* __restrict__ bn_b,
    const float* __restrict__ bn_m, const float* __restrict__ bn_v,
    float* __restrict__ h1p, int N) {
    int n = (int)((blockIdx.x * blockDim.x + threadIdx.x) >> 6);
    if (n >= N) return;
    int lane = threadIdx.x & 63;
    int hl = lane >> 4;              // head for channels lane*2, lane*2+1
    int c0 = lane * 2;

    // self loop
    float wself = __expf(lrelu(as1[n * 4 + hl] + ad1[n * 4 + hl]));
    unsigned int hs = ((const unsigned int*)(h1g + (size_t)n * 128))[lane];
    float accA0 = wself * bf2f((unsigned short)hs);
    float accA1 = wself * bf2f((unsigned short)(hs >> 16));
    float ssA = wself;
    float accB0 = 0.f, accB1 = 0.f, ssB = 0.f;

    int beg = rowptr[n], end = rowptr[n + 1];
    int idx = beg;
    for (; idx + 1 < end; idx += 2) {
        int s0 = csrSD[idx].x, s1 = csrSD[idx + 1].x;
        float p0 = csrW[idx * 4 + hl];
        float p1 = csrW[(idx + 1) * 4 + hl];
        unsigned int u0 = ((const unsigned int*)(h1g + (size_t)s0 * 128))[lane];
        unsigned int u1 = ((const unsigned int*)(h1g + (size_t)s1 * 128))[lane];
        accA0 = fmaf(p0, bf2f((unsigned short)u0), accA0);
        accA1 = fmaf(p0, bf2f((unsigned short)(u0 >> 16)), accA1);
        ssA += p0;
        accB0 = fmaf(p1, bf2f((unsigned short)u1), accB0);
        accB1 = fmaf(p1, bf2f((unsigned short)(u1 >> 16)), accB1);
        ssB += p1;
    }
    if (idx < end) {
        int s0 = csrSD[idx].x;
        float p0 = csrW[idx * 4 + hl];
        unsigned int u0 = ((const unsigned int*)(h1g + (size_t)s0 * 128))[lane];
        accA0 = fmaf(p0, bf2f((unsigned short)u0), accA0);
        accA1 = fmaf(p0, bf2f((unsigned short)(u0 >> 16)), accA1);
        ssA += p0;
    }
    float inv = 1.f / (ssA + ssB);
    float o[2] = {(accA0 + accB0) * inv, (accA1 + accB1) * inv};
    #pragma unroll
    for (int u = 0; u < 2; u++) {
        int c = c0 + u;
        float v = o[u] + b1[c];
        v = (v - bn_m[c]) * rsqrtf(bn_v[c] + BN_EPS) * bn_g[c] + bn_b[c];
        o[u] = (v > 0.f) ? v : expm1f(v);
    }
    *(float2*)(h1p + (size_t)n * 128 + c0) = make_float2(o[0], o[1]);
}

// ---------------------------------------------------------------- GEMM2: h2g(bf16) = h1p @ W2 (+ scalar alpha epilogue)
__global__ __launch_bounds__(256) void gemm2_kernel(
    const float* __restrict__ A, const float* __restrict__ W,
    const float* __restrict__ a_src, const float* __restrict__ a_dst,
    unsigned short* __restrict__ h2g, float* __restrict__ as2, float* __restrict__ ad2, int N) {
    __shared__ float As[64][33];
    __shared__ float Bs[32][32];
    int tid = threadIdx.x;
    int tx = tid & 31, ty = tid >> 5;
    int rowBase = blockIdx.x * 64;
    float acc[8];
    #pragma unroll
    for (int i = 0; i < 8; i++) acc[i] = 0.f;
    for (int k0 = 0; k0 < 128; k0 += 32) {
        #pragma unroll
        for (int u = 0; u < 2; u++) {
            int ff = tid * 2 + u;
            int r = ff >> 3, c = (ff & 7) * 4;
            float4 v = make_float4(0.f, 0.f, 0.f, 0.f);
            int gr = rowBase + r;
            if (gr < N) v = *(const float4*)(A + (size_t)gr * 128 + k0 + c);
            As[r][c] = v.x; As[r][c + 1] = v.y; As[r][c + 2] = v.z; As[r][c + 3] = v.w;
        }
        {
            int r = tid >> 3, c = (tid & 7) * 4;
            *(float4*)&Bs[r][c] = *(const float4*)(W + (size_t)(k0 + r) * 32 + c);
        }
        __syncthreads();
        #pragma unroll
        for (int kk = 0; kk < 32; kk++) {
            float b = Bs[kk][tx];
            #pragma unroll
            for (int i = 0; i < 8; i++) acc[i] = fmaf(As[ty * 8 + i][kk], b, acc[i]);
        }
        __syncthreads();
    }
    float aws = a_src[tx], awd = a_dst[tx];
    #pragma unroll
    for (int i = 0; i < 8; i++) {
        int gr = rowBase + ty * 8 + i;
        float v = acc[i];
        float ps = v * aws, pd = v * awd;
        #pragma unroll
        for (int off = 1; off < 32; off <<= 1) { ps += __shfl_xor(ps, off); pd += __shfl_xor(pd, off); }
        if (gr < N) {
            h2g[(size_t)gr * 32 + tx] = f2bf(v);
            if (tx == 0) { as2[gr] = ps; ad2[gr] = pd; }
        }
    }
}

// ---------------------------------------------------------------- agg2: 2 nodes/wave, bf16 gather (64B/row), unroll x2
__global__ __launch_bounds__(256) void agg2_kernel(
    const unsigned short* __restrict__ h2g,
    const float* __restrict__ as2, const float* __restrict__ ad2,
    const int* __restrict__ rowptr, const int2* __restrict__ csrSD, const float* __restrict__ w2,
    const float* __restrict__ b2, float* __restrict__ hl2, int N) {
    int wid = (int)((blockIdx.x * blockDim.x + threadIdx.x) >> 6);
    int lane = threadIdx.x & 63;
    int half = lane >> 5;
    int c = lane & 31;
    int n = wid * 2 + half;
    bool valid = (n < N);
    int nc = valid ? n : (N - 1);

    float ws = __expf(lrelu(as2[nc] + ad2[nc]));
    float hs = bf2f(h2g[(size_t)nc * 32 + c]);
    float accA = ws * hs, ssA = ws, accB = 0.f, ssB = 0.f;

    int beg = rowptr[nc], end = rowptr[nc + 1];
    int idx = beg;
    for (; idx + 1 < end; idx += 2) {
        int s0 = csrSD[idx].x, s1 = csrSD[idx + 1].x;
        float p0 = w2[idx], p1 = w2[idx + 1];
        float v0 = bf2f(h2g[(size_t)s0 * 32 + c]);
        float v1 = bf2f(h2g[(size_t)s1 * 32 + c]);
        accA = fmaf(p0, v0, accA); ssA += p0;
        accB = fmaf(p1, v1, accB); ssB += p1;
    }
    if (idx < end) {
        int s0 = csrSD[idx].x;
        float p0 = w2[idx];
        float v0 = bf2f(h2g[(size_t)s0 * 32 + c]);
        accA = fmaf(p0, v0, accA); ssA += p0;
    }
    if (valid) hl2[(size_t)n * 32 + c] = (accA + accB) / (ssA + ssB) + b2[c];
}

// ---------------------------------------------------------------- fused head
__global__ __launch_bounds__(256) void head_kernel(
    const float* __restrict__ context, const float* __restrict__ hl2,
    const float* __restrict__ rw1, const float* __restrict__ rb1,
    const float* __restrict__ rw2, const float* __restrict__ rb2,
    const float* __restrict__ dw, const float* __restrict__ db,
    const float* __restrict__ cw, const float* __restrict__ cb,
    float* __restrict__ out_lsm, float* __restrict__ out_expl, int N) {
    __shared__ float s_rw1[192], s_rw2[1024], s_dw[1024], s_cw[320];
    __shared__ float s_rb1[32], s_rb2[32], s_db[32], s_cb[10];
    int tid = threadIdx.x;
    for (int i = tid; i < 192; i += 256) s_rw1[i] = rw1[i];
    for (int i = tid; i < 1024; i += 256) { s_rw2[i] = rw2[i]; s_dw[i] = dw[i]; }
    for (int i = tid; i < 320; i += 256) s_cw[i] = cw[i];
    if (tid < 32) { s_rb1[tid] = rb1[tid]; s_rb2[tid] = rb2[tid]; s_db[tid] = db[tid]; }
    if (tid < 10) s_cb[tid] = cb[tid];
    __syncthreads();
    int n = blockIdx.x * 256 + tid;
    if (n >= N) return;

    float ctx[6];
    #pragma unroll
    for (int i = 0; i < 6; i++) ctx[i] = context[(size_t)n * 6 + i];

    float t1[32];
    #pragma unroll
    for (int c = 0; c < 32; c++) t1[c] = s_rb1[c];
    #pragma unroll
    for (int i = 0; i < 6; i++) {
        float s = ctx[i];
        #pragma unroll
        for (int c = 0; c < 32; c++) t1[c] = fmaf(s, s_rw1[i * 32 + c], t1[c]);
    }
    #pragma unroll
    for (int c = 0; c < 32; c++) t1[c] = fmaxf(t1[c], 0.f);

    float ex[32];
    #pragma unroll
    for (int c = 0; c < 32; c++) ex[c] = s_rb2[c];
    #pragma unroll
    for (int c = 0; c < 32; c++) {
        float s = t1[c];
        #pragma unroll
        for (int c2 = 0; c2 < 32; c2++) ex[c2] = fmaf(s, s_rw2[c * 32 + c2], ex[c2]);
    }
    #pragma unroll
    for (int c = 0; c < 32; c += 4)
        *(float4*)(out_expl + (size_t)n * 32 + c) = make_float4(ex[c], ex[c + 1], ex[c + 2], ex[c + 3]);

    float rec[32];
    #pragma unroll
    for (int k = 0; k < 32; k++) rec[k] = s_db[k];
    #pragma unroll
    for (int c = 0; c < 32; c++) {
        float s = ex[c];
        #pragma unroll
        for (int k = 0; k < 32; k++) rec[k] = fmaf(s, s_dw[c * 32 + k], rec[k]);
    }
    float comb[32];
    #pragma unroll
    for (int k = 0; k < 32; k += 4) {
        float4 h = *(const float4*)(hl2 + (size_t)n * 32 + k);
        comb[k] = h.x + RECON_W * rec[k];
        comb[k + 1] = h.y + RECON_W * rec[k + 1];
        comb[k + 2] = h.z + RECON_W * rec[k + 2];
        comb[k + 3] = h.w + RECON_W * rec[k + 3];
    }
    float lg[10];
    #pragma unroll
    for (int j = 0; j < 10; j++) lg[j] = s_cb[j];
    #pragma unroll
    for (int k = 0; k < 32; k++) {
        float s = comb[k];
        #pragma unroll
        for (int j = 0; j < 10; j++) lg[j] = fmaf(s, s_cw[k * 10 + j], lg[j]);
    }
    float mx = lg[0];
    #pragma unroll
    for (int j = 1; j < 10; j++) mx = fmaxf(mx, lg[j]);
    float se = 0.f;
    #pragma unroll
    for (int j = 0; j < 10; j++) se += expf(lg[j] - mx);
    float lse = mx + logf(se);
    #pragma unroll
    for (int j = 0; j < 10; j++) out_lsm[(size_t)n * 10 + j] = lg[j] - lse;
}

// ---------------------------------------------------------------- launch
extern "C" void kernel_launch(void* const* d_in, const int* in_sizes, int n_in,
                              void* d_out, int out_size, void* d_ws, size_t ws_size,
                              hipStream_t stream) {
    const float* x    = (const float*)d_in[0];
    const int* ei     = (const int*)d_in[1];
    const float* ctx  = (const float*)d_in[2];
    const float* W1   = (const float*)d_in[3];
    const float* a_s1 = (const float*)d_in[4];
    const float* a_d1 = (const float*)d_in[5];
    const float* b1   = (const float*)d_in[6];
    const float* bn_g = (const float*)d_in[7];
    const float* bn_b = (const float*)d_in[8];
    const float* bn_m = (const float*)d_in[9];
    const float* bn_v = (const float*)d_in[10];
    const float* W2   = (const float*)d_in[11];
    const float* a_s2 = (const float*)d_in[12];
    const float* a_d2 = (const float*)d_in[13];
    const float* b2   = (const float*)d_in[14];
    const float* rw1  = (const float*)d_in[15];
    const float* rb1  = (const float*)d_in[16];
    const float* rw2  = (const float*)d_in[17];
    const float* rb2  = (const float*)d_in[18];
    const float* dw   = (const float*)d_in[19];
    const float* db   = (const float*)d_in[20];
    const float* cw   = (const float*)d_in[21];
    const float* cb   = (const float*)d_in[22];

    int N = in_sizes[0] / 128;
    int E = in_sizes[1] / 2;
    const int* esrc = ei;
    const int* edst = ei + E;

    char* w = (char*)d_ws;
    auto alloc = [&](size_t bytes) {
        void* p = (void*)w;
        w += (bytes + 255) & ~(size_t)255;
        return p;
    };
    unsigned short* h1g = (unsigned short*)alloc((size_t)N * 128 * 2);  // bf16 gather table L1
    float* h1p  = (float*)alloc((size_t)N * 128 * 4);                   // fp32 activated L1 out
    unsigned short* h2g = (unsigned short*)alloc((size_t)N * 32 * 2);   // bf16 gather table L2
    float* hl2  = (float*)alloc((size_t)N * 32 * 4);
    float* as1  = (float*)alloc((size_t)N * 4 * 4);
    float* ad1  = (float*)alloc((size_t)N * 4 * 4);
    float* as2  = (float*)alloc((size_t)N * 4);
    float* ad2  = (float*)alloc((size_t)N * 4);
    int* deg    = (int*)alloc((size_t)N * 2 * 4);   // deg + cursor adjacent, one memset
    int* cursor = deg + N;
    int* rowptr = (int*)alloc((size_t)(N + 1) * 4);
    int2* csrSD = (int2*)alloc((size_t)E * 8);
    float* csrW = (float*)alloc((size_t)E * 4 * 4);
    float* w2   = (float*)alloc((size_t)E * 4);

    float* out0 = (float*)d_out;            // log_softmax [N,10]
    float* out1 = out0 + (size_t)N * 10;    // expl [N,32]

    hipMemsetAsync(deg, 0, (size_t)N * 2 * 4, stream);

    count_kernel<<<(E + 255) / 256, 256, 0, stream>>>(edst, E, deg);
    scan_kernel<<<1, 1024, 0, stream>>>(deg, rowptr, N);
    gemm1_kernel<<<(N + 63) / 64, 256, 0, stream>>>(x, W1, a_s1, a_d1, h1g, as1, ad1, N);
    scatter_kernel<<<(E + 255) / 256, 256, 0, stream>>>(esrc, edst, E, rowptr, cursor, csrSD);
    weight1_kernel<<<(E + 255) / 256, 256, 0, stream>>>(csrSD, E, as1, ad1, csrW);
    agg1_kernel<<<(N + 3) / 4, 256, 0, stream>>>(h1g, as1, ad1, rowptr, csrSD, csrW,
                                                 b1, bn_g, bn_b, bn_m, bn_v, h1p, N);
    gemm2_kernel<<<(N + 63) / 64, 256, 0, stream>>>(h1p, W2, a_s2, a_d2, h2g, as2, ad2, N);
    weight2_kernel<<<(E + 255) / 256, 256, 0, stream>>>(csrSD, E, as2, ad2, w2);
    agg2_kernel<<<(N + 7) / 8, 256, 0, stream>>>(h2g, as2, ad2, rowptr, csrSD, w2, b2, hl2, N);
    head_kernel<<<(N + 255) / 256, 256, 0, stream>>>(ctx, hl2, rw1, rb1, rw2, rb2,
                                                     dw, db, cw, cb, out0, out1, N);
}

// Round 4
// 455.679 us; speedup vs baseline: 1.2937x; 1.0687x over previous
//
#include <hip/hip_runtime.h>
#include <hip/hip_bf16.h>
#include <math.h>

#define NEG_SLOPE 0.2f
#define RECON_W 0.1f
#define BN_EPS 1e-5f

__device__ __forceinline__ float lrelu(float v) {
    return (v >= 0.f) ? v : NEG_SLOPE * v;
}
// fp32 -> bf16 (round-to-nearest-even, finite inputs)
__device__ __forceinline__ unsigned short f2bf(float f) {
    unsigned int u = __float_as_uint(f);
    u = (u + 0x7fffu + ((u >> 16) & 1u)) >> 16;
    return (unsigned short)u;
}
__device__ __forceinline__ float bf2f(unsigned short u) {
    return __uint_as_float(((unsigned int)u) << 16);
}
__device__ __forceinline__ unsigned int pack2bf(float a, float b) {
    return (unsigned int)f2bf(a) | ((unsigned int)f2bf(b) << 16);
}
__device__ __forceinline__ void unpack2(unsigned int u, float& a, float& b) {
    a = bf2f((unsigned short)u);
    b = bf2f((unsigned short)(u >> 16));
}

// ---------------------------------------------------------------- CSR build
__global__ void count_kernel(const int* __restrict__ dst, int E, int* __restrict__ deg) {
    int e = blockIdx.x * blockDim.x + threadIdx.x;
    if (e < E) atomicAdd(&deg[dst[e]], 1);
}

// per-4096-chunk partial sums
__global__ __launch_bounds__(256) void partsum_kernel(const int* __restrict__ deg, int N,
                                                      int* __restrict__ bsums) {
    int b = blockIdx.x, tid = threadIdx.x;
    int base = b * 4096;
    int sum = 0;
    #pragma unroll
    for (int it = 0; it < 4; it++) {
        int i0 = base + (it * 256 + tid) * 4;
        if (i0 + 3 < N) {
            int4 v = *(const int4*)(deg + i0);
            sum += v.x + v.y + v.z + v.w;
        } else {
            #pragma unroll
            for (int j = 0; j < 4; j++) if (i0 + j < N) sum += deg[i0 + j];
        }
    }
    #pragma unroll
    for (int off = 32; off >= 1; off >>= 1) sum += __shfl_xor(sum, off);
    __shared__ int ws[4];
    if ((tid & 63) == 0) ws[tid >> 6] = sum;
    __syncthreads();
    if (tid == 0) bsums[b] = ws[0] + ws[1] + ws[2] + ws[3];
}

// local scan of 4096 + global offset, write rowptr
__global__ __launch_bounds__(1024) void scanwrite_kernel(const int* __restrict__ deg,
                                                         const int* __restrict__ bsums,
                                                         int* __restrict__ rowptr,
                                                         int N, int E, int nb) {
    __shared__ int wsum[16];
    __shared__ int s_base;
    int tid = threadIdx.x, b = blockIdx.x;
    int lane = tid & 63, w = tid >> 6;
    if (w == 0) {   // first wave computes this block's base offset
        int x = (lane < b && lane < nb) ? bsums[lane] : 0;
        #pragma unroll
        for (int off = 32; off >= 1; off >>= 1) x += __shfl_xor(x, off);
        if (lane == 0) s_base = x;
    }
    if (b == 0 && tid == 0) rowptr[N] = E;

    int i0 = b * 4096 + tid * 4;
    int4 v4 = make_int4(0, 0, 0, 0);
    if (i0 + 3 < N) {
        v4 = *(const int4*)(deg + i0);
    } else {
        if (i0 < N) v4.x = deg[i0];
        if (i0 + 1 < N) v4.y = deg[i0 + 1];
        if (i0 + 2 < N) v4.z = deg[i0 + 2];
    }
    int v = v4.x + v4.y + v4.z + v4.w;
    int inc = v;
    #pragma unroll
    for (int off = 1; off < 64; off <<= 1) {
        int t = __shfl_up(inc, off);
        if (lane >= off) inc += t;
    }
    if (lane == 63) wsum[w] = inc;
    __syncthreads();
    if (tid == 0) {
        int r = 0;
        #pragma unroll
        for (int j = 0; j < 16; j++) { int t = wsum[j]; wsum[j] = r; r += t; }
    }
    __syncthreads();
    int excl = s_base + wsum[w] + inc - v;
    if (i0 + 3 < N) {
        *(int4*)(rowptr + i0) = make_int4(excl, excl + v4.x, excl + v4.x + v4.y,
                                          excl + v4.x + v4.y + v4.z);
    } else {
        if (i0 < N) rowptr[i0] = excl;
        if (i0 + 1 < N) rowptr[i0 + 1] = excl + v4.x;
        if (i0 + 2 < N) rowptr[i0 + 2] = excl + v4.x + v4.y;
    }
}

// scatter: int2{src,dst} per CSR slot
__global__ void scatter_kernel(const int* __restrict__ src, const int* __restrict__ dst, int E,
                               const int* __restrict__ rowptr, int* __restrict__ cursor,
                               int2* __restrict__ csrSD) {
    int e = blockIdx.x * blockDim.x + threadIdx.x;
    if (e >= E) return;
    int s = src[e], d = dst[e];
    int pos = rowptr[d] + atomicAdd(&cursor[d], 1);
    csrSD[pos] = make_int2(s, d);
}

// layer-1 edge weights, coalesced over CSR positions
__global__ void weight1_kernel(const int2* __restrict__ csrSD, int E,
                               const float* __restrict__ as1, const float* __restrict__ ad1,
                               float* __restrict__ csrW) {
    int e = blockIdx.x * blockDim.x + threadIdx.x;
    if (e >= E) return;
    int2 sd = csrSD[e];
    float4 av = *(const float4*)(as1 + (size_t)sd.x * 4);
    float4 bv = *(const float4*)(ad1 + (size_t)sd.y * 4);
    float4 wv;
    wv.x = __expf(lrelu(av.x + bv.x));
    wv.y = __expf(lrelu(av.y + bv.y));
    wv.z = __expf(lrelu(av.z + bv.z));
    wv.w = __expf(lrelu(av.w + bv.w));
    *(float4*)(csrW + (size_t)e * 4) = wv;
}

// layer-2 edge weights
__global__ void weight2_kernel(const int2* __restrict__ csrSD, int E,
                               const float* __restrict__ as2, const float* __restrict__ ad2,
                               float* __restrict__ w2) {
    int e = blockIdx.x * blockDim.x + threadIdx.x;
    if (e >= E) return;
    int2 sd = csrSD[e];
    w2[e] = __expf(lrelu(as2[sd.x] + ad2[sd.y]));
}

// fold bias+BN into per-channel scale/shift
__global__ void bnprep_kernel(const float* __restrict__ b1, const float* __restrict__ g,
                              const float* __restrict__ be, const float* __restrict__ m,
                              const float* __restrict__ v,
                              float* __restrict__ scale, float* __restrict__ shift) {
    int c = threadIdx.x;   // 128
    float s = rsqrtf(v[c] + BN_EPS) * g[c];
    scale[c] = s;
    shift[c] = (b1[c] - m[c]) * s + be[c];
}

// ---------------------------------------------------------------- GEMM1: h1g(bf16) = x @ W1 (+ alpha epilogue)
__global__ __launch_bounds__(256) void gemm1_kernel(
    const float* __restrict__ x, const float* __restrict__ W,
    const float* __restrict__ a_src, const float* __restrict__ a_dst,
    unsigned short* __restrict__ h1g, float* __restrict__ as1, float* __restrict__ ad1, int N) {
    __shared__ float As[64][33];
    __shared__ float Bs[32][128];
    int tid = threadIdx.x;
    int tx = tid & 15;
    int ty = tid >> 4;
    int rowBase = blockIdx.x * 64;
    float acc[4][8];
    #pragma unroll
    for (int i = 0; i < 4; i++)
        #pragma unroll
        for (int j = 0; j < 8; j++) acc[i][j] = 0.f;

    for (int k0 = 0; k0 < 128; k0 += 32) {
        #pragma unroll
        for (int u = 0; u < 2; u++) {
            int ff = tid * 2 + u;
            int r = ff >> 3, c = (ff & 7) * 4;
            float4 v = make_float4(0.f, 0.f, 0.f, 0.f);
            int gr = rowBase + r;
            if (gr < N) v = *(const float4*)(x + (size_t)gr * 128 + k0 + c);
            As[r][c] = v.x; As[r][c + 1] = v.y; As[r][c + 2] = v.z; As[r][c + 3] = v.w;
        }
        #pragma unroll
        for (int u = 0; u < 4; u++) {
            int ff = tid + u * 256;
            int r = ff >> 5, c = (ff & 31) * 4;
            *(float4*)&Bs[r][c] = *(const float4*)(W + (size_t)(k0 + r) * 128 + c);
        }
        __syncthreads();
        #pragma unroll
        for (int kk = 0; kk < 32; kk++) {
            float aa[4];
            #pragma unroll
            for (int i = 0; i < 4; i++) aa[i] = As[ty * 4 + i][kk];
            float4 b0 = *(float4*)&Bs[kk][tx * 8];
            float4 b1 = *(float4*)&Bs[kk][tx * 8 + 4];
            float bb[8] = {b0.x, b0.y, b0.z, b0.w, b1.x, b1.y, b1.z, b1.w};
            #pragma unroll
            for (int i = 0; i < 4; i++)
                #pragma unroll
                for (int j = 0; j < 8; j++) acc[i][j] = fmaf(aa[i], bb[j], acc[i][j]);
        }
        __syncthreads();
    }
    int head = tx >> 2, sub = tx & 3;
    float wsv[8], wdv[8];
    #pragma unroll
    for (int j = 0; j < 8; j++) {
        wsv[j] = a_src[head * 32 + sub * 8 + j];
        wdv[j] = a_dst[head * 32 + sub * 8 + j];
    }
    #pragma unroll
    for (int i = 0; i < 4; i++) {
        int gr = rowBase + ty * 4 + i;
        float ps = 0.f, pd = 0.f;
        #pragma unroll
        for (int j = 0; j < 8; j++) { ps = fmaf(acc[i][j], wsv[j], ps); pd = fmaf(acc[i][j], wdv[j], pd); }
        ps += __shfl_xor(ps, 1); ps += __shfl_xor(ps, 2);
        pd += __shfl_xor(pd, 1); pd += __shfl_xor(pd, 2);
        if (gr < N) {
            uint4 pk;
            pk.x = pack2bf(acc[i][0], acc[i][1]);
            pk.y = pack2bf(acc[i][2], acc[i][3]);
            pk.z = pack2bf(acc[i][4], acc[i][5]);
            pk.w = pack2bf(acc[i][6], acc[i][7]);
            *(uint4*)(h1g + (size_t)gr * 128 + tx * 8) = pk;
            if (sub == 0) { as1[gr * 4 + head] = ps; ad1[gr * 4 + head] = pd; }
        }
    }
}

// ---------------------------------------------------------------- agg1: wave/node, half-wave per edge, 4ch/lane
__global__ __launch_bounds__(256) void agg1_kernel(
    const unsigned short* __restrict__ h1g,
    const float* __restrict__ as1, const float* __restrict__ ad1,
    const int* __restrict__ rowptr, const int2* __restrict__ csrSD, const float* __restrict__ csrW,
    const float* __restrict__ bnscale, const float* __restrict__ bnshift,
    unsigned short* __restrict__ h1p, int N) {
    int n = (int)((blockIdx.x * blockDim.x + threadIdx.x) >> 6);
    if (n >= N) return;
    int lane = threadIdx.x & 63;
    int half = lane >> 5;
    int l = lane & 31;        // channels l*4 .. l*4+3
    int hl = l >> 3;          // head

    float wself = __expf(lrelu(as1[n * 4 + hl] + ad1[n * 4 + hl]));
    float acc0 = 0.f, acc1 = 0.f, acc2 = 0.f, acc3 = 0.f, ss = 0.f;
    if (half == 0) {
        uint2 u = *(const uint2*)(h1g + (size_t)n * 128 + l * 4);
        float f0, f1, f2, f3;
        unpack2(u.x, f0, f1); unpack2(u.y, f2, f3);
        acc0 = wself * f0; acc1 = wself * f1; acc2 = wself * f2; acc3 = wself * f3;
        ss = wself;
    }
    int beg = rowptr[n], end = rowptr[n + 1];
    for (int idx = beg + half; idx < end; idx += 2) {
        int s = csrSD[idx].x;
        float p = csrW[idx * 4 + hl];
        uint2 u = *(const uint2*)(h1g + (size_t)s * 128 + l * 4);
        float f0, f1, f2, f3;
        unpack2(u.x, f0, f1); unpack2(u.y, f2, f3);
        acc0 = fmaf(p, f0, acc0); acc1 = fmaf(p, f1, acc1);
        acc2 = fmaf(p, f2, acc2); acc3 = fmaf(p, f3, acc3);
        ss += p;
    }
    acc0 += __shfl_xor(acc0, 32); acc1 += __shfl_xor(acc1, 32);
    acc2 += __shfl_xor(acc2, 32); acc3 += __shfl_xor(acc3, 32);
    ss += __shfl_xor(ss, 32);
    if (half == 0) {
        float inv = 1.f / ss;
        float4 sc = *(const float4*)(bnscale + l * 4);
        float4 sh = *(const float4*)(bnshift + l * 4);
        float o0 = fmaf(acc0 * inv, sc.x, sh.x);
        float o1 = fmaf(acc1 * inv, sc.y, sh.y);
        float o2 = fmaf(acc2 * inv, sc.z, sh.z);
        float o3 = fmaf(acc3 * inv, sc.w, sh.w);
        o0 = (o0 > 0.f) ? o0 : expm1f(o0);
        o1 = (o1 > 0.f) ? o1 : expm1f(o1);
        o2 = (o2 > 0.f) ? o2 : expm1f(o2);
        o3 = (o3 > 0.f) ? o3 : expm1f(o3);
        uint2 pk;
        pk.x = pack2bf(o0, o1);
        pk.y = pack2bf(o2, o3);
        *(uint2*)(h1p + (size_t)n * 128 + l * 4) = pk;
    }
}

// ---------------------------------------------------------------- GEMM2: h2g(bf16) = h1p(bf16) @ W2 (+ alpha epilogue)
__global__ __launch_bounds__(256) void gemm2_kernel(
    const unsigned short* __restrict__ A, const float* __restrict__ W,
    const float* __restrict__ a_src, const float* __restrict__ a_dst,
    unsigned short* __restrict__ h2g, float* __restrict__ as2, float* __restrict__ ad2, int N) {
    __shared__ float As[64][33];
    __shared__ float Bs[32][32];
    int tid = threadIdx.x;
    int tx = tid & 31, ty = tid >> 5;
    int rowBase = blockIdx.x * 64;
    float acc[8];
    #pragma unroll
    for (int i = 0; i < 8; i++) acc[i] = 0.f;
    for (int k0 = 0; k0 < 128; k0 += 32) {
        {
            int r = tid >> 2, c = (tid & 3) * 8;   // 64 rows x 32 cols, 8 bf16/thread
            int gr = rowBase + r;
            uint4 u = make_uint4(0, 0, 0, 0);
            if (gr < N) u = *(const uint4*)(A + (size_t)gr * 128 + k0 + c);
            float f0, f1;
            unpack2(u.x, f0, f1); As[r][c] = f0; As[r][c + 1] = f1;
            unpack2(u.y, f0, f1); As[r][c + 2] = f0; As[r][c + 3] = f1;
            unpack2(u.z, f0, f1); As[r][c + 4] = f0; As[r][c + 5] = f1;
            unpack2(u.w, f0, f1); As[r][c + 6] = f0; As[r][c + 7] = f1;
        }
        {
            int r = tid >> 3, c = (tid & 7) * 4;
            *(float4*)&Bs[r][c] = *(const float4*)(W + (size_t)(k0 + r) * 32 + c);
        }
        __syncthreads();
        #pragma unroll
        for (int kk = 0; kk < 32; kk++) {
            float b = Bs[kk][tx];
            #pragma unroll
            for (int i = 0; i < 8; i++) acc[i] = fmaf(As[ty * 8 + i][kk], b, acc[i]);
        }
        __syncthreads();
    }
    float aws = a_src[tx], awd = a_dst[tx];
    #pragma unroll
    for (int i = 0; i < 8; i++) {
        int gr = rowBase + ty * 8 + i;
        float v = acc[i];
        float ps = v * aws, pd = v * awd;
        #pragma unroll
        for (int off = 1; off < 32; off <<= 1) { ps += __shfl_xor(ps, off); pd += __shfl_xor(pd, off); }
        if (gr < N) {
            h2g[(size_t)gr * 32 + tx] = f2bf(v);
            if (tx == 0) { as2[gr] = ps; ad2[gr] = pd; }
        }
    }
}

// ---------------------------------------------------------------- agg2: wave/node, quarter-wave per edge, 2ch/lane
__global__ __launch_bounds__(256) void agg2_kernel(
    const unsigned short* __restrict__ h2g,
    const float* __restrict__ as2, const float* __restrict__ ad2,
    const int* __restrict__ rowptr, const int2* __restrict__ csrSD, const float* __restrict__ w2,
    const float* __restrict__ b2, float* __restrict__ hl2, int N) {
    int n = (int)((blockIdx.x * blockDim.x + threadIdx.x) >> 6);
    if (n >= N) return;
    int lane = threadIdx.x & 63;
    int q = lane >> 4;
    int l = lane & 15;        // channels l*2, l*2+1

    float wself = __expf(lrelu(as2[n] + ad2[n]));
    float acc0 = 0.f, acc1 = 0.f, ss = 0.f;
    if (q == 0) {
        unsigned int u = *(const unsigned int*)(h2g + (size_t)n * 32 + l * 2);
        float f0, f1; unpack2(u, f0, f1);
        acc0 = wself * f0; acc1 = wself * f1; ss = wself;
    }
    int beg = rowptr[n], end = rowptr[n + 1];
    for (int idx = beg + q; idx < end; idx += 4) {
        int s = csrSD[idx].x;
        float p = w2[idx];
        unsigned int u = *(const unsigned int*)(h2g + (size_t)s * 32 + l * 2);
        float f0, f1; unpack2(u, f0, f1);
        acc0 = fmaf(p, f0, acc0); acc1 = fmaf(p, f1, acc1);
        ss += p;
    }
    acc0 += __shfl_xor(acc0, 16); acc1 += __shfl_xor(acc1, 16); ss += __shfl_xor(ss, 16);
    acc0 += __shfl_xor(acc0, 32); acc1 += __shfl_xor(acc1, 32); ss += __shfl_xor(ss, 32);
    if (lane < 16) {
        float inv = 1.f / ss;
        float2 o = make_float2(acc0 * inv + b2[l * 2], acc1 * inv + b2[l * 2 + 1]);
        *(float2*)(hl2 + (size_t)n * 32 + l * 2) = o;
    }
}

// ---------------------------------------------------------------- fused head
__global__ __launch_bounds__(256) void head_kernel(
    const float* __restrict__ context, const float* __restrict__ hl2,
    const float* __restrict__ rw1, const float* __restrict__ rb1,
    const float* __restrict__ rw2, const float* __restrict__ rb2,
    const float* __restrict__ dw, const float* __restrict__ db,
    const float* __restrict__ cw, const float* __restrict__ cb,
    float* __restrict__ out_lsm, float* __restrict__ out_expl, int N) {
    __shared__ float s_rw1[192], s_rw2[1024], s_dw[1024], s_cw[320];
    __shared__ float s_rb1[32], s_rb2[32], s_db[32], s_cb[10];
    int tid = threadIdx.x;
    for (int i = tid; i < 192; i += 256) s_rw1[i] = rw1[i];
    for (int i = tid; i < 1024; i += 256) { s_rw2[i] = rw2[i]; s_dw[i] = dw[i]; }
    for (int i = tid; i < 320; i += 256) s_cw[i] = cw[i];
    if (tid < 32) { s_rb1[tid] = rb1[tid]; s_rb2[tid] = rb2[tid]; s_db[tid] = db[tid]; }
    if (tid < 10) s_cb[tid] = cb[tid];
    __syncthreads();
    int n = blockIdx.x * 256 + tid;
    if (n >= N) return;

    float ctx[6];
    #pragma unroll
    for (int i = 0; i < 6; i++) ctx[i] = context[(size_t)n * 6 + i];

    float t1[32];
    #pragma unroll
    for (int c = 0; c < 32; c++) t1[c] = s_rb1[c];
    #pragma unroll
    for (int i = 0; i < 6; i++) {
        float s = ctx[i];
        #pragma unroll
        for (int c = 0; c < 32; c++) t1[c] = fmaf(s, s_rw1[i * 32 + c], t1[c]);
    }
    #pragma unroll
    for (int c = 0; c < 32; c++) t1[c] = fmaxf(t1[c], 0.f);

    float ex[32];
    #pragma unroll
    for (int c = 0; c < 32; c++) ex[c] = s_rb2[c];
    #pragma unroll
    for (int c = 0; c < 32; c++) {
        float s = t1[c];
        #pragma unroll
        for (int c2 = 0; c2 < 32; c2++) ex[c2] = fmaf(s, s_rw2[c * 32 + c2], ex[c2]);
    }
    #pragma unroll
    for (int c = 0; c < 32; c += 4)
        *(float4*)(out_expl + (size_t)n * 32 + c) = make_float4(ex[c], ex[c + 1], ex[c + 2], ex[c + 3]);

    float rec[32];
    #pragma unroll
    for (int k = 0; k < 32; k++) rec[k] = s_db[k];
    #pragma unroll
    for (int c = 0; c < 32; c++) {
        float s = ex[c];
        #pragma unroll
        for (int k = 0; k < 32; k++) rec[k] = fmaf(s, s_dw[c * 32 + k], rec[k]);
    }
    float comb[32];
    #pragma unroll
    for (int k = 0; k < 32; k += 4) {
        float4 h = *(const float4*)(hl2 + (size_t)n * 32 + k);
        comb[k] = h.x + RECON_W * rec[k];
        comb[k + 1] = h.y + RECON_W * rec[k + 1];
        comb[k + 2] = h.z + RECON_W * rec[k + 2];
        comb[k + 3] = h.w + RECON_W * rec[k + 3];
    }
    float lg[10];
    #pragma unroll
    for (int j = 0; j < 10; j++) lg[j] = s_cb[j];
    #pragma unroll
    for (int k = 0; k < 32; k++) {
        float s = comb[k];
        #pragma unroll
        for (int j = 0; j < 10; j++) lg[j] = fmaf(s, s_cw[k * 10 + j], lg[j]);
    }
    float mx = lg[0];
    #pragma unroll
    for (int j = 1; j < 10; j++) mx = fmaxf(mx, lg[j]);
    float se = 0.f;
    #pragma unroll
    for (int j = 0; j < 10; j++) se += expf(lg[j] - mx);
    float lse = mx + logf(se);
    #pragma unroll
    for (int j = 0; j < 10; j++) out_lsm[(size_t)n * 10 + j] = lg[j] - lse;
}

// ---------------------------------------------------------------- launch
extern "C" void kernel_launch(void* const* d_in, const int* in_sizes, int n_in,
                              void* d_out, int out_size, void* d_ws, size_t ws_size,
                              hipStream_t stream) {
    const float* x    = (const float*)d_in[0];
    const int* ei     = (const int*)d_in[1];
    const float* ctx  = (const float*)d_in[2];
    const float* W1   = (const float*)d_in[3];
    const float* a_s1 = (const float*)d_in[4];
    const float* a_d1 = (const float*)d_in[5];
    const float* b1   = (const float*)d_in[6];
    const float* bn_g = (const float*)d_in[7];
    const float* bn_b = (const float*)d_in[8];
    const float* bn_m = (const float*)d_in[9];
    const float* bn_v = (const float*)d_in[10];
    const float* W2   = (const float*)d_in[11];
    const float* a_s2 = (const float*)d_in[12];
    const float* a_d2 = (const float*)d_in[13];
    const float* b2   = (const float*)d_in[14];
    const float* rw1  = (const float*)d_in[15];
    const float* rb1  = (const float*)d_in[16];
    const float* rw2  = (const float*)d_in[17];
    const float* rb2  = (const float*)d_in[18];
    const float* dw   = (const float*)d_in[19];
    const float* db   = (const float*)d_in[20];
    const float* cw   = (const float*)d_in[21];
    const float* cb   = (const float*)d_in[22];

    int N = in_sizes[0] / 128;
    int E = in_sizes[1] / 2;
    const int* esrc = ei;
    const int* edst = ei + E;
    int nb = (N + 4095) / 4096;

    char* w = (char*)d_ws;
    auto alloc = [&](size_t bytes) {
        void* p = (void*)w;
        w += (bytes + 255) & ~(size_t)255;
        return p;
    };
    unsigned short* h1g = (unsigned short*)alloc((size_t)N * 128 * 2);  // bf16 gather table L1
    unsigned short* h1p = (unsigned short*)alloc((size_t)N * 128 * 2);  // bf16 activated L1 out
    unsigned short* h2g = (unsigned short*)alloc((size_t)N * 32 * 2);   // bf16 gather table L2
    float* hl2  = (float*)alloc((size_t)N * 32 * 4);
    float* as1  = (float*)alloc((size_t)N * 4 * 4);
    float* ad1  = (float*)alloc((size_t)N * 4 * 4);
    float* as2  = (float*)alloc((size_t)N * 4);
    float* ad2  = (float*)alloc((size_t)N * 4);
    int* deg    = (int*)alloc((size_t)N * 2 * 4);   // deg + cursor adjacent, one memset
    int* cursor = deg + N;
    int* rowptr = (int*)alloc((size_t)(N + 1) * 4);
    int* bsums  = (int*)alloc((size_t)nb * 4);
    int2* csrSD = (int2*)alloc((size_t)E * 8);
    float* csrW = (float*)alloc((size_t)E * 4 * 4);
    float* w2   = (float*)alloc((size_t)E * 4);
    float* bnsc = (float*)alloc(128 * 4);
    float* bnsh = (float*)alloc(128 * 4);

    float* out0 = (float*)d_out;            // log_softmax [N,10]
    float* out1 = out0 + (size_t)N * 10;    // expl [N,32]

    hipMemsetAsync(deg, 0, (size_t)N * 2 * 4, stream);

    count_kernel<<<(E + 255) / 256, 256, 0, stream>>>(edst, E, deg);
    partsum_kernel<<<nb, 256, 0, stream>>>(deg, N, bsums);
    scanwrite_kernel<<<nb, 1024, 0, stream>>>(deg, bsums, rowptr, N, E, nb);
    gemm1_kernel<<<(N + 63) / 64, 256, 0, stream>>>(x, W1, a_s1, a_d1, h1g, as1, ad1, N);
    scatter_kernel<<<(E + 255) / 256, 256, 0, stream>>>(esrc, edst, E, rowptr, cursor, csrSD);
    weight1_kernel<<<(E + 255) / 256, 256, 0, stream>>>(csrSD, E, as1, ad1, csrW);
    bnprep_kernel<<<1, 128, 0, stream>>>(b1, bn_g, bn_b, bn_m, bn_v, bnsc, bnsh);
    agg1_kernel<<<(N + 3) / 4, 256, 0, stream>>>(h1g, as1, ad1, rowptr, csrSD, csrW,
                                                 bnsc, bnsh, h1p, N);
    gemm2_kernel<<<(N + 63) / 64, 256, 0, stream>>>(h1p, W2, a_s2, a_d2, h2g, as2, ad2, N);
    weight2_kernel<<<(E + 255) / 256, 256, 0, stream>>>(csrSD, E, as2, ad2, w2);
    agg2_kernel<<<(N + 3) / 4, 256, 0, stream>>>(h2g, as2, ad2, rowptr, csrSD, w2, b2, hl2, N);
    head_kernel<<<(N + 255) / 256, 256, 0, stream>>>(ctx, hl2, rw1, rb1, rw2, rb2,
                                                     dw, db, cw, cb, out0, out1, N);
}